// Round 11
// baseline (349.815 us; speedup 1.0000x reference)
//
#include <hip/hip_runtime.h>
#include <hip/hip_fp16.h>
#include <math.h>

#define BB 2
#define SS 2048
#define EE 1024
#define HH 16
#define DD 64
#define YAT_EPS 1e-5f
#define RR (BB * HH * SS)   // 65536 attention rows

typedef __attribute__((ext_vector_type(8))) short bf16x8;
typedef __attribute__((ext_vector_type(4))) short short4v;
typedef __attribute__((ext_vector_type(4))) float f32x4;
#define MFMA16(a, b, c) __builtin_amdgcn_mfma_f32_16x16x32_bf16((a), (b), (c), 0, 0, 0)

#if __has_builtin(__builtin_amdgcn_exp2f)
#define EXP2(x) __builtin_amdgcn_exp2f(x)
#else
#define EXP2(x) exp2f(x)
#endif
#if __has_builtin(__builtin_amdgcn_rcpf)
#define RCPF(x) __builtin_amdgcn_rcpf(x)
#else
#define RCPF(x) (1.0f / (x))
#endif

__device__ __forceinline__ unsigned short f2bf(float x) {
    unsigned int u = __float_as_uint(x);
    u += 0x7FFFu + ((u >> 16) & 1u);   // RNE
    return (unsigned short)(u >> 16);
}
__device__ __forceinline__ float bf2f(unsigned short h) {
    return __uint_as_float(((unsigned int)h) << 16);
}
// truncating fp32->bf16 (1 op; P >= 0, relative bias ~0.1% — renorm-safe)
__device__ __forceinline__ short f2bf_t(float x) {
    return (short)(__float_as_uint(x) >> 16);
}

__device__ __forceinline__ void async_ld16(void* lds, const void* g) {
    __builtin_amdgcn_global_load_lds(
        (const __attribute__((address_space(1))) unsigned int*)g,
        (__attribute__((address_space(3))) unsigned int*)lds, 16, 0, 0);
}

// Merged input/weight hi-lo split, one launch.
// bid in [0,4096): x -> xhi/xlo. bid in [4096,8192): weights; lo for Wq,Wk.
__global__ __launch_bounds__(256) void split_all(
        const float* __restrict__ x,
        const float* __restrict__ Wq, const float* __restrict__ Wk,
        const float* __restrict__ Wv, const float* __restrict__ Wo,
        unsigned short* __restrict__ xhi, unsigned short* __restrict__ xlo,
        unsigned short* __restrict__ Whi, unsigned short* __restrict__ Wlo,
        unsigned short* __restrict__ Wohi) {
    const int bid = blockIdx.x;
    if (bid < 4096) {
        int i = bid * 256 + threadIdx.x;
        float4 v = ((const float4*)x)[i];
        ushort4 h, l;
        h.x = f2bf(v.x); l.x = f2bf(v.x - bf2f(h.x));
        h.y = f2bf(v.y); l.y = f2bf(v.y - bf2f(h.y));
        h.z = f2bf(v.z); l.z = f2bf(v.z - bf2f(h.z));
        h.w = f2bf(v.w); l.w = f2bf(v.w - bf2f(h.w));
        ((ushort4*)xhi)[i] = h;
        ((ushort4*)xlo)[i] = l;
    } else {
        int idx = bid - 4096;
        int y = idx >> 10;
        int i = (idx & 1023) * 256 + threadIdx.x;       // < EE*EE/4
        const float* src = y == 0 ? Wq : y == 1 ? Wk : y == 2 ? Wv : Wo;
        unsigned short* hi = y < 3 ? Whi + (size_t)y * EE * EE : Wohi;
        float4 v = ((const float4*)src)[i];
        ushort4 h;
        h.x = f2bf(v.x); h.y = f2bf(v.y); h.z = f2bf(v.z); h.w = f2bf(v.w);
        ((ushort4*)hi)[i] = h;
        if (y < 2) {
            unsigned short* lo = Wlo + (size_t)y * EE * EE;
            ushort4 l;
            l.x = f2bf(v.x - bf2f(h.x));
            l.y = f2bf(v.y - bf2f(h.y));
            l.z = f2bf(v.z - bf2f(h.z));
            l.w = f2bf(v.w - bf2f(h.w));
            ((ushort4*)lo)[i] = l;
        }
    }
}

// Fused Q/K/V projection, BK=64 (half the barrier count of the BK=32
// version; LDS 64KB -> residency unchanged: the (256,2) register cap
// already limits to 2 blocks/CU, and 160/64 = 2).
// grid.x in [0,16): QK tiles over N=2048 concat [Wq;Wk], 3-pass Markidis.
// grid.x in [16,24): V tiles, 1-pass, epilogue = in-LDS transpose -> vt.
__global__ __launch_bounds__(256, 2) void proj_qkv(
        const unsigned short* __restrict__ Ahi, const unsigned short* __restrict__ Alo,
        const unsigned short* __restrict__ Whi, const unsigned short* __restrict__ Wlo,
        const float* __restrict__ bq, const float* __restrict__ bk,
        const float* __restrict__ bv,
        unsigned short* __restrict__ qhi, unsigned short* __restrict__ qlo,
        unsigned short* __restrict__ khi, unsigned short* __restrict__ vt,
        float* __restrict__ sqn, float* __restrict__ skn) {
    // 4 staging buffers of [128][64] shorts (16KB each, 64KB total).
    // V epilogue reuses the region as a 128x136 transpose tile (34.8KB).
    __shared__ __align__(16) unsigned short SH[4 * 8192];
    unsigned short* LA_hi = SH;
    unsigned short* LA_lo = SH + 8192;
    unsigned short* LB_hi = SH + 16384;
    unsigned short* LB_lo = SH + 24576;

    const int K = EE;
    const int t = threadIdx.x;
    const int w = t >> 6, lane = t & 63;
    const int quad = lane >> 4, lr = lane & 15;
    const int wy = w & 1, wx = w >> 1;
    const bool p3 = blockIdx.x < 16;             // 3-pass (QK) vs 1-pass (V)
    const int m0 = blockIdx.y * 128;
    const int n0 = p3 ? blockIdx.x * 128 : 0;
    const int c0 = p3 ? 0 : (blockIdx.x - 16) * 128;

    const unsigned short* gsrc = nullptr;
    unsigned short* ldst = nullptr;
    if (w == 0)      { gsrc = Ahi + (size_t)m0 * K; ldst = LA_hi; }
    else if (w == 2) {
        gsrc = p3 ? Whi + (size_t)n0 * K
                  : Whi + (size_t)(2 * EE + c0) * K;   // Wv rows
        ldst = LB_hi;
    } else if (p3 && w == 1) { gsrc = Alo + (size_t)m0 * K; ldst = LA_lo; }
    else if (p3 && w == 3)   { gsrc = Wlo + (size_t)n0 * K; ldst = LB_lo; }
    // lane l covers row (l>>3)+8j, 16B chunk (l&7) of the 64-wide window
    const unsigned short* gl = gsrc ? gsrc + (size_t)(lane >> 3) * K + (lane & 7) * 8
                                    : nullptr;

    f32x4 acc[4][4];
    #pragma unroll
    for (int i = 0; i < 4; ++i)
        #pragma unroll
        for (int j = 0; j < 4; ++j)
            acc[i][j] = (f32x4){0.f, 0.f, 0.f, 0.f};

    for (int k0 = 0; k0 < K; k0 += 64) {
        __syncthreads();
        if (gl) {
            #pragma unroll
            for (int j = 0; j < 16; ++j)
                async_ld16(ldst + j * 512, gl + (size_t)j * 8 * K + k0);
        }
        __syncthreads();
        #pragma unroll
        for (int kk = 0; kk < 2; ++kk) {
            bf16x8 ah[4], al[4], bh_[4], bl_[4];
            #pragma unroll
            for (int i = 0; i < 4; ++i) {
                ah[i]  = *(const bf16x8*)&LA_hi[(wy * 64 + i * 16 + lr) * 64
                                                + kk * 32 + quad * 8];
                bh_[i] = *(const bf16x8*)&LB_hi[(wx * 64 + i * 16 + lr) * 64
                                                + kk * 32 + quad * 8];
                if (p3) {
                    al[i]  = *(const bf16x8*)&LA_lo[(wy * 64 + i * 16 + lr) * 64
                                                    + kk * 32 + quad * 8];
                    bl_[i] = *(const bf16x8*)&LB_lo[(wx * 64 + i * 16 + lr) * 64
                                                    + kk * 32 + quad * 8];
                }
            }
            #pragma unroll
            for (int mg = 0; mg < 4; ++mg)
                #pragma unroll
                for (int ns = 0; ns < 4; ++ns) {
                    f32x4 a = acc[mg][ns];
                    a = MFMA16(ah[mg], bh_[ns], a);
                    if (p3) {
                        a = MFMA16(ah[mg], bl_[ns], a);
                        a = MFMA16(al[mg], bh_[ns], a);
                    }
                    acc[mg][ns] = a;
                }
        }
    }

    if (p3) {
        const int ng = n0 + wx * 64;
        const int path = ng >> 10;               // 0=q 1=k
        const int c = ng & 1023;
        const int h = c >> 6;
        const float* bias = path == 0 ? bq : bk;
        unsigned short* hi_p = path == 0 ? qhi : khi;
        float* nrm = path == 0 ? sqn : skn;
        float bias_v[4];
        #pragma unroll
        for (int ns = 0; ns < 4; ++ns) bias_v[ns] = bias[c + ns * 16 + lr];
        #pragma unroll
        for (int mg = 0; mg < 4; ++mg)
            #pragma unroll
            for (int r = 0; r < 4; ++r) {
                int m = m0 + wy * 64 + mg * 16 + quad * 4 + r;
                int b = m >> 11, s = m & (SS - 1);
                size_t base = ((size_t)(b * HH + h) * SS + s) * DD;
                float v4[4];
                #pragma unroll
                for (int ns = 0; ns < 4; ++ns) v4[ns] = acc[mg][ns][r] + bias_v[ns];
                float pn = v4[0] * v4[0] + v4[1] * v4[1] + v4[2] * v4[2] + v4[3] * v4[3];
                #pragma unroll
                for (int off = 1; off < 16; off <<= 1) pn += __shfl_xor(pn, off);
                if (lr == 0) nrm[(size_t)(b * HH + h) * SS + s] = pn;
                #pragma unroll
                for (int ns = 0; ns < 4; ++ns) {
                    unsigned short hv = f2bf(v4[ns]);
                    hi_p[base + ns * 16 + lr] = hv;
                    if (path == 0)
                        qlo[base + ns * 16 + lr] = f2bf(v4[ns] - bf2f(hv));
                }
            }
    } else {
        // V path: in-LDS transpose, write vt[bh][d][s] directly.
        __syncthreads();                          // staging reads all retired
        float bias_v[4];
        #pragma unroll
        for (int ns = 0; ns < 4; ++ns) bias_v[ns] = bv[c0 + wx * 64 + ns * 16 + lr];
        #pragma unroll
        for (int mg = 0; mg < 4; ++mg)
            #pragma unroll
            for (int r = 0; r < 4; ++r) {
                int mloc = wy * 64 + mg * 16 + quad * 4 + r;
                #pragma unroll
                for (int ns = 0; ns < 4; ++ns) {
                    int cloc = wx * 64 + ns * 16 + lr;
                    SH[cloc * 136 + mloc] = f2bf(acc[mg][ns][r] + bias_v[ns]);
                }
            }
        __syncthreads();
        const int b = m0 >> 11, s0 = m0 & (SS - 1);
        #pragma unroll
        for (int jc = 0; jc < 8; ++jc) {
            int cl = (t >> 4) + jc * 16;          // transposed line 0..127
            int sl = (t & 15) * 8;                // 16 lanes cover 128 s
            bf16x8 vv = *(const bf16x8*)&SH[cl * 136 + sl];
            int c = c0 + cl, h = c >> 6, d = c & 63;
            *(bf16x8*)&vt[((size_t)(b * HH + h) * DD + d) * SS + s0 + sl] = vv;
        }
    }
}

// bf16 MFMA GEMM (O-projection, 1-pass, BK=64).
__global__ __launch_bounds__(256, 2) void gemm_o(
        const unsigned short* __restrict__ Ahi,
        const unsigned short* __restrict__ Bhi,
        const float* __restrict__ bq,
        float* __restrict__ Cf,
        int M, int N, int K) {
    __shared__ __align__(16) unsigned short LA_hi[128 * 64];
    __shared__ __align__(16) unsigned short LB_hi[128 * 64];

    const int t = threadIdx.x;
    const int w = t >> 6, lane = t & 63;
    const int quad = lane >> 4, lr = lane & 15;
    const int wy = w & 1, wx = w >> 1;
    const int m0 = blockIdx.y * 128, n0 = blockIdx.x * 128;

    const unsigned short* gsrc = nullptr;
    unsigned short* ldst = nullptr;
    if (w == 0)      { gsrc = Ahi + (size_t)m0 * K; ldst = LA_hi; }
    else if (w == 2) { gsrc = Bhi + (size_t)n0 * K; ldst = LB_hi; }
    const unsigned short* gl = gsrc ? gsrc + (size_t)(lane >> 3) * K + (lane & 7) * 8
                                    : nullptr;

    f32x4 acc[4][4];
    #pragma unroll
    for (int i = 0; i < 4; ++i)
        #pragma unroll
        for (int j = 0; j < 4; ++j)
            acc[i][j] = (f32x4){0.f, 0.f, 0.f, 0.f};

    for (int k0 = 0; k0 < K; k0 += 64) {
        __syncthreads();
        if (gl) {
            #pragma unroll
            for (int j = 0; j < 16; ++j)
                async_ld16(ldst + j * 512, gl + (size_t)j * 8 * K + k0);
        }
        __syncthreads();
        #pragma unroll
        for (int kk = 0; kk < 2; ++kk) {
            bf16x8 ah[4], bh_[4];
            #pragma unroll
            for (int i = 0; i < 4; ++i) {
                ah[i]  = *(const bf16x8*)&LA_hi[(wy * 64 + i * 16 + lr) * 64
                                                + kk * 32 + quad * 8];
                bh_[i] = *(const bf16x8*)&LB_hi[(wx * 64 + i * 16 + lr) * 64
                                                + kk * 32 + quad * 8];
            }
            #pragma unroll
            for (int mg = 0; mg < 4; ++mg)
                #pragma unroll
                for (int ns = 0; ns < 4; ++ns)
                    acc[mg][ns] = MFMA16(ah[mg], bh_[ns], acc[mg][ns]);
        }
    }

    const int ng = n0 + wx * 64;
    float bias_v[4];
    #pragma unroll
    for (int ns = 0; ns < 4; ++ns) bias_v[ns] = bq[ng + ns * 16 + lr];
    #pragma unroll
    for (int mg = 0; mg < 4; ++mg)
        #pragma unroll
        for (int r = 0; r < 4; ++r) {
            int m = m0 + wy * 64 + mg * 16 + quad * 4 + r;
            #pragma unroll
            for (int ns = 0; ns < 4; ++ns)
                Cf[(size_t)m * N + ng + ns * 16 + lr] = acc[mg][ns][r] + bias_v[ns];
        }
}

// MFMA flash attention v15 (round-8 measured best: 159.2us, VGPR 64,
// LDS 25088, WRITE 8.2MB, zero conflicts) — restored VERBATIM.
// z=1 (32 tiles/block, 1024 blocks), fused normalize + bf16 ctx epilogue.
// K staged via global_load_lds, XOR-swizzled, double-buffered, 64-key tile
// per buffer, full-tile prefetch distance. Ps single-buffered. defer-max.
__global__ __launch_bounds__(256, 4) void yat_attn_mfma(
        const unsigned short* __restrict__ qhi, const unsigned short* __restrict__ qlo,
        const unsigned short* __restrict__ khi,
        const unsigned short* __restrict__ vt,
        const float* __restrict__ sqn, const float* __restrict__ skn,
        const float* __restrict__ alphap,
        unsigned short* __restrict__ ctxhi) {
    __shared__ __align__(16) unsigned short Ks[2][4096];     // [dbuf][64k x 64d] 16KB
    __shared__ __align__(16) unsigned short Ps[4][16 * 68];  // [wave] 8.7KB

    const int t = threadIdx.x;
    const int w = t >> 6, lane = t & 63;
    const int quad = lane >> 4, lr = lane & 15;
    const int qt = blockIdx.x, bh = blockIdx.y;
    const int row0 = qt * 64 + w * 16;
    const float cscale = powf(sqrtf((float)DD) / log1pf((float)DD), alphap[0])
                         * 1.4426950408889634f;

    bf16x8 qh[2], ql[2];
    #pragma unroll
    for (int kd = 0; kd < 2; ++kd) {
        size_t o = ((size_t)bh * SS + row0 + lr) * DD + kd * 32 + quad * 8;
        qh[kd] = *(const bf16x8*)&qhi[o];
        ql[kd] = *(const bf16x8*)&qlo[o];
    }
    const float sqe = sqn[(size_t)bh * SS + row0 + lr] + YAT_EPS;

    const int lrow = lane >> 3;
    const int lofs = lrow * 64 + (((lane & 7) ^ (lrow & 7)) << 3);
    const int sw = lr & 7;

    float m_r = -INFINITY, l_r = 0.f;   // m_r in u-domain
    f32x4 O[4];
    #pragma unroll
    for (int nd = 0; nd < 4; ++nd) O[nd] = (f32x4){0.f, 0.f, 0.f, 0.f};

    const size_t khi_base = (size_t)bh * SS * 64 + (size_t)w * 16 * 64 + lofs;
    const size_t skn_base = (size_t)bh * SS + quad * 4;
    unsigned short* myP = Ps[w];

    // prologue: stage tile 0 into buffer 0 (wave w stages rows w*16..+15)
    #pragma unroll
    for (int i2 = 0; i2 < 2; ++i2)
        async_ld16(&Ks[0][w * 1024 + i2 * 512], khi + khi_base + i2 * 512);

    for (int it = 0; it < 32; ++it) {
        const int p = it & 1;
        __syncthreads();           // drains vmcnt: buffer p is ready
        if (it + 1 < 32) {
            #pragma unroll
            for (int i2 = 0; i2 < 2; ++i2)
                async_ld16(&Ks[p ^ 1][w * 1024 + i2 * 512],
                           khi + khi_base + (size_t)(it + 1) * 4096 + i2 * 512);
        }
        const int kbase = it * 64;
        const unsigned short* kb = Ks[p];
        f32x4 acc[4];
        f32x4 sk4[4];
        #pragma unroll
        for (int st = 0; st < 4; ++st) {
            const int rbase = (st * 16 + lr) * 64;
            bf16x8 kh0 = *(const bf16x8*)&kb[rbase + ((quad    ) ^ sw) * 8];
            bf16x8 kh1 = *(const bf16x8*)&kb[rbase + ((quad + 4) ^ sw) * 8];
            sk4[st] = *(const f32x4*)&skn[skn_base + kbase + st * 16];
            f32x4 a = (f32x4){0.f, 0.f, 0.f, 0.f};
            a = MFMA16(kh0, qh[0], a);
            a = MFMA16(kh1, qh[1], a);
            a = MFMA16(kh0, ql[0], a);
            a = MFMA16(kh1, ql[1], a);
            acc[st] = a;
        }
        bf16x8 vf[4][2];
        #pragma unroll
        for (int nd = 0; nd < 4; ++nd)
            #pragma unroll
            for (int kk = 0; kk < 2; ++kk)
                vf[nd][kk] = *(const bf16x8*)&vt[((size_t)bh * DD + nd * 16 + lr) * SS
                                                 + kbase + kk * 32 + quad * 8];
        float mx = -INFINITY;
        #pragma unroll
        for (int st = 0; st < 4; ++st)
            #pragma unroll
            for (int r = 0; r < 4; ++r) {
                float qk = acc[st][r];
                float d = sqe + sk4[st][r] - 2.f * qk;
                float u = qk * qk * RCPF(d);
                acc[st][r] = u;
                mx = fmaxf(mx, u);
            }
        mx = fmaxf(mx, __shfl_xor(mx, 16));
        mx = fmaxf(mx, __shfl_xor(mx, 32));
        float mnew = fmaxf(m_r, mx);
        // defer-max: only rescale when some row's max grew by >8 (exp2 domain)
        bool resc = !__all(cscale * (mnew - m_r) <= 8.f);
        float aa = 1.f;
        if (resc) {
            aa = EXP2(__builtin_fmaf(cscale, m_r, -cscale * mnew));
            m_r = mnew;
        }
        const float cm = cscale * m_r;
        float rs = 0.f;
        #pragma unroll
        for (int st = 0; st < 4; ++st) {
            float e0 = EXP2(__builtin_fmaf(cscale, acc[st][0], -cm));
            float e1 = EXP2(__builtin_fmaf(cscale, acc[st][1], -cm));
            float e2 = EXP2(__builtin_fmaf(cscale, acc[st][2], -cm));
            float e3 = EXP2(__builtin_fmaf(cscale, acc[st][3], -cm));
            rs += (e0 + e1) + (e2 + e3);
            short4v pv;
            pv[0] = f2bf_t(e0); pv[1] = f2bf_t(e1);
            pv[2] = f2bf_t(e2); pv[3] = f2bf_t(e3);
            *(short4v*)&myP[lr * 68 + st * 16 + quad * 4] = pv;
        }
        rs += __shfl_xor(rs, 16);
        rs += __shfl_xor(rs, 32);
        l_r = l_r * aa + rs;
        if (resc) {
            float al_[4];
            #pragma unroll
            for (int r = 0; r < 4; ++r) al_[r] = __shfl(aa, quad * 4 + r);
            #pragma unroll
            for (int nd = 0; nd < 4; ++nd)
                #pragma unroll
                for (int r = 0; r < 4; ++r)
                    O[nd][r] *= al_[r];
        }
        bf16x8 pf[2];
        #pragma unroll
        for (int kk = 0; kk < 2; ++kk)
            pf[kk] = *(const bf16x8*)&myP[lr * 68 + kk * 32 + quad * 8];
        #pragma unroll
        for (int nd = 0; nd < 4; ++nd)
            #pragma unroll
            for (int kk = 0; kk < 2; ++kk)
                O[nd] = MFMA16(pf[kk], vf[nd][kk], O[nd]);
    }
    // fused epilogue: normalize by 1/l and write ctx bf16 directly.
    const int b = bh >> 4, h = bh & 15;
    #pragma unroll
    for (int r = 0; r < 4; ++r) {
        float li = __shfl(l_r, quad * 4 + r);
        float inv = RCPF(li);
        int s = row0 + quad * 4 + r;
        size_t base = ((size_t)b * SS + s) * EE + h * DD;
        #pragma unroll
        for (int nd = 0; nd < 4; ++nd)
            ctxhi[base + nd * 16 + lr] = f2bf(O[nd][r] * inv);
    }
}

extern "C" void kernel_launch(void* const* d_in, const int* in_sizes, int n_in,
                              void* d_out, int out_size, void* d_ws, size_t ws_size,
                              hipStream_t stream) {
    const float* x     = (const float*)d_in[0];
    const float* Wq    = (const float*)d_in[1];
    const float* bq    = (const float*)d_in[2];
    const float* Wk    = (const float*)d_in[3];
    const float* bk    = (const float*)d_in[4];
    const float* Wv    = (const float*)d_in[5];
    const float* bv    = (const float*)d_in[6];
    const float* Wo    = (const float*)d_in[7];
    const float* bo    = (const float*)d_in[8];
    const float* alpha = (const float*)d_in[9];
    float* out = (float*)d_out;
    char* ws = (char*)d_ws;

    const int M = BB * SS;                 // 4096
    const size_t MB = 1u << 20;
    unsigned short* xhi  = (unsigned short*)(ws + 0 * MB);   // later: ctxhi
    unsigned short* xlo  = (unsigned short*)(ws + 8 * MB);
    unsigned short* Whi  = (unsigned short*)(ws + 16 * MB);  // 6 MB (qkv concat)
    unsigned short* Wlo  = (unsigned short*)(ws + 22 * MB);  // 4 MB used (q,k)
    unsigned short* Wohi = (unsigned short*)(ws + 28 * MB);
    unsigned short* qhi  = (unsigned short*)(ws + 32 * MB);
    unsigned short* qlo  = (unsigned short*)(ws + 40 * MB);
    unsigned short* khi  = (unsigned short*)(ws + 48 * MB);  // 8 MB
    unsigned short* vt   = (unsigned short*)(ws + 56 * MB);  // 8 MB
    float* sqn = (float*)(ws + 80 * MB);
    float* skn = (float*)(ws + 80 * MB + 256 * 1024);
    unsigned short* ctxhi = xhi;           // xhi dead after proj_qkv

    split_all<<<8192, 256, 0, stream>>>(x, Wq, Wk, Wv, Wo,
                                        xhi, xlo, Whi, Wlo, Wohi);

    // Fused Q/K (3-pass Markidis) + V (1-pass, transposed-write) projection
    proj_qkv<<<dim3(24, M / 128), 256, 0, stream>>>(
        xhi, xlo, Whi, Wlo, bq, bk, bv,
        qhi, qlo, khi, vt, sqn, skn);

    // attention (single K-range pass, fused normalize + ctx write)
    yat_attn_mfma<<<dim3(SS / 64, BB * HH), 256, 0, stream>>>(
        qhi, qlo, khi, vt, sqn, skn, alpha, ctxhi);

    // O projection: plain bf16 (error ~6e-4 ≪ threshold)
    gemm_o<<<dim3(EE / 128, M / 128), 256, 0, stream>>>(
        ctxhi, Wohi, bo, out, M, EE, EE);
}

// Round 12
// 317.257 us; speedup vs baseline: 1.1026x; 1.1026x over previous
//
#include <hip/hip_runtime.h>
#include <hip/hip_fp16.h>
#include <math.h>

#define BB 2
#define SS 2048
#define EE 1024
#define HH 16
#define DD 64
#define YAT_EPS 1e-5f
#define RR (BB * HH * SS)   // 65536 attention rows

typedef __attribute__((ext_vector_type(8))) short bf16x8;
typedef __attribute__((ext_vector_type(4))) short short4v;
typedef __attribute__((ext_vector_type(4))) float f32x4;
#define MFMA16(a, b, c) __builtin_amdgcn_mfma_f32_16x16x32_bf16((a), (b), (c), 0, 0, 0)

#if __has_builtin(__builtin_amdgcn_exp2f)
#define EXP2(x) __builtin_amdgcn_exp2f(x)
#else
#define EXP2(x) exp2f(x)
#endif
#if __has_builtin(__builtin_amdgcn_rcpf)
#define RCPF(x) __builtin_amdgcn_rcpf(x)
#else
#define RCPF(x) (1.0f / (x))
#endif

__device__ __forceinline__ unsigned short f2bf(float x) {
    unsigned int u = __float_as_uint(x);
    u += 0x7FFFu + ((u >> 16) & 1u);   // RNE
    return (unsigned short)(u >> 16);
}
__device__ __forceinline__ float bf2f(unsigned short h) {
    return __uint_as_float(((unsigned int)h) << 16);
}
// truncating fp32->bf16 (1 op; P >= 0, relative bias ~0.1% — renorm-safe)
__device__ __forceinline__ short f2bf_t(float x) {
    return (short)(__float_as_uint(x) >> 16);
}

__device__ __forceinline__ void async_ld16(void* lds, const void* g) {
    __builtin_amdgcn_global_load_lds(
        (const __attribute__((address_space(1))) unsigned int*)g,
        (__attribute__((address_space(3))) unsigned int*)lds, 16, 0, 0);
}

// Merged input/weight hi-lo split, one launch.
// bid in [0,4096): x -> xhi/xlo. bid in [4096,8192): weights; lo for Wq,Wk.
__global__ __launch_bounds__(256) void split_all(
        const float* __restrict__ x,
        const float* __restrict__ Wq, const float* __restrict__ Wk,
        const float* __restrict__ Wv, const float* __restrict__ Wo,
        unsigned short* __restrict__ xhi, unsigned short* __restrict__ xlo,
        unsigned short* __restrict__ Whi, unsigned short* __restrict__ Wlo,
        unsigned short* __restrict__ Wohi) {
    const int bid = blockIdx.x;
    if (bid < 4096) {
        int i = bid * 256 + threadIdx.x;
        float4 v = ((const float4*)x)[i];
        ushort4 h, l;
        h.x = f2bf(v.x); l.x = f2bf(v.x - bf2f(h.x));
        h.y = f2bf(v.y); l.y = f2bf(v.y - bf2f(h.y));
        h.z = f2bf(v.z); l.z = f2bf(v.z - bf2f(h.z));
        h.w = f2bf(v.w); l.w = f2bf(v.w - bf2f(h.w));
        ((ushort4*)xhi)[i] = h;
        ((ushort4*)xlo)[i] = l;
    } else {
        int idx = bid - 4096;
        int y = idx >> 10;
        int i = (idx & 1023) * 256 + threadIdx.x;       // < EE*EE/4
        const float* src = y == 0 ? Wq : y == 1 ? Wk : y == 2 ? Wv : Wo;
        unsigned short* hi = y < 3 ? Whi + (size_t)y * EE * EE : Wohi;
        float4 v = ((const float4*)src)[i];
        ushort4 h;
        h.x = f2bf(v.x); h.y = f2bf(v.y); h.z = f2bf(v.z); h.w = f2bf(v.w);
        ((ushort4*)hi)[i] = h;
        if (y < 2) {
            unsigned short* lo = Wlo + (size_t)y * EE * EE;
            ushort4 l;
            l.x = f2bf(v.x - bf2f(h.x));
            l.y = f2bf(v.y - bf2f(h.y));
            l.z = f2bf(v.z - bf2f(h.z));
            l.w = f2bf(v.w - bf2f(h.w));
            ((ushort4*)lo)[i] = l;
        }
    }
}

// Fused Q/K/V projection, single launch. BK=32 (round-8 measured best;
// round 11 proved BK=64's 64KB LDS halves residency 4->2 blocks/CU: +27us).
// grid.x in [0,16): QK tiles over N=2048 concat [Wq;Wk], 3-pass Markidis,
//   epilogue = bf16 hi(+lo for q) [B,H,S,D] + fp32 norms.
// grid.x in [16,24): V tiles over N=1024, plain bf16 1-pass, epilogue =
//   in-LDS 128x128 transpose writing vt[bh][d][s] DIRECTLY.
__global__ __launch_bounds__(256, 2) void proj_qkv(
        const unsigned short* __restrict__ Ahi, const unsigned short* __restrict__ Alo,
        const unsigned short* __restrict__ Whi, const unsigned short* __restrict__ Wlo,
        const float* __restrict__ bq, const float* __restrict__ bk,
        const float* __restrict__ bv,
        unsigned short* __restrict__ qhi, unsigned short* __restrict__ qlo,
        unsigned short* __restrict__ khi, unsigned short* __restrict__ vt,
        float* __restrict__ sqn, float* __restrict__ skn) {
    // SH aliases: QK path = 4 stage buffers (16384 shorts);
    // V epilogue = 128x136 transpose tile (17408 shorts, stride 136 keeps
    // 16B alignment for b128 reads; staging buffers are dead by then).
    __shared__ __align__(16) unsigned short SH[128 * 136];
    unsigned short* LA_hi = SH;
    unsigned short* LA_lo = SH + 4096;
    unsigned short* LB_hi = SH + 8192;
    unsigned short* LB_lo = SH + 12288;

    const int K = EE;
    const int t = threadIdx.x;
    const int w = t >> 6, lane = t & 63;
    const int quad = lane >> 4, lr = lane & 15;
    const int wy = w & 1, wx = w >> 1;
    const bool p3 = blockIdx.x < 16;             // 3-pass (QK) vs 1-pass (V)
    const int m0 = blockIdx.y * 128;
    const int n0 = p3 ? blockIdx.x * 128 : 0;
    const int c0 = p3 ? 0 : (blockIdx.x - 16) * 128;

    const unsigned short* gsrc = nullptr;
    unsigned short* ldst = nullptr;
    if (w == 0)      { gsrc = Ahi + (size_t)m0 * K; ldst = LA_hi; }
    else if (w == 2) {
        gsrc = p3 ? Whi + (size_t)n0 * K
                  : Whi + (size_t)(2 * EE + c0) * K;   // Wv rows
        ldst = LB_hi;
    } else if (p3 && w == 1) { gsrc = Alo + (size_t)m0 * K; ldst = LA_lo; }
    else if (p3 && w == 3)   { gsrc = Wlo + (size_t)n0 * K; ldst = LB_lo; }
    const unsigned short* gl = gsrc ? gsrc + (size_t)(lane >> 2) * K + (lane & 3) * 8
                                    : nullptr;

    f32x4 acc[4][4];
    #pragma unroll
    for (int i = 0; i < 4; ++i)
        #pragma unroll
        for (int j = 0; j < 4; ++j)
            acc[i][j] = (f32x4){0.f, 0.f, 0.f, 0.f};

    for (int k0 = 0; k0 < K; k0 += 32) {
        __syncthreads();
        if (gl) {
            #pragma unroll
            for (int i = 0; i < 8; ++i)
                async_ld16(ldst + i * 512, gl + (size_t)i * 16 * K + k0);
        }
        __syncthreads();
        bf16x8 ah[4], al[4], bh_[4], bl_[4];
        #pragma unroll
        for (int i = 0; i < 4; ++i) {
            ah[i]  = *(const bf16x8*)&LA_hi[(wy * 64 + i * 16 + lr) * 32 + quad * 8];
            bh_[i] = *(const bf16x8*)&LB_hi[(wx * 64 + i * 16 + lr) * 32 + quad * 8];
            if (p3) {
                al[i]  = *(const bf16x8*)&LA_lo[(wy * 64 + i * 16 + lr) * 32 + quad * 8];
                bl_[i] = *(const bf16x8*)&LB_lo[(wx * 64 + i * 16 + lr) * 32 + quad * 8];
            }
        }
        #pragma unroll
        for (int mg = 0; mg < 4; ++mg)
            #pragma unroll
            for (int ns = 0; ns < 4; ++ns) {
                f32x4 a = acc[mg][ns];
                a = MFMA16(ah[mg], bh_[ns], a);
                if (p3) {
                    a = MFMA16(ah[mg], bl_[ns], a);
                    a = MFMA16(al[mg], bh_[ns], a);
                }
                acc[mg][ns] = a;
            }
    }

    if (p3) {
        const int ng = n0 + wx * 64;
        const int path = ng >> 10;               // 0=q 1=k
        const int c = ng & 1023;
        const int h = c >> 6;
        const float* bias = path == 0 ? bq : bk;
        unsigned short* hi_p = path == 0 ? qhi : khi;
        float* nrm = path == 0 ? sqn : skn;
        float bias_v[4];
        #pragma unroll
        for (int ns = 0; ns < 4; ++ns) bias_v[ns] = bias[c + ns * 16 + lr];
        #pragma unroll
        for (int mg = 0; mg < 4; ++mg)
            #pragma unroll
            for (int r = 0; r < 4; ++r) {
                int m = m0 + wy * 64 + mg * 16 + quad * 4 + r;
                int b = m >> 11, s = m & (SS - 1);
                size_t base = ((size_t)(b * HH + h) * SS + s) * DD;
                float v4[4];
                #pragma unroll
                for (int ns = 0; ns < 4; ++ns) v4[ns] = acc[mg][ns][r] + bias_v[ns];
                float pn = v4[0] * v4[0] + v4[1] * v4[1] + v4[2] * v4[2] + v4[3] * v4[3];
                #pragma unroll
                for (int off = 1; off < 16; off <<= 1) pn += __shfl_xor(pn, off);
                if (lr == 0) nrm[(size_t)(b * HH + h) * SS + s] = pn;
                #pragma unroll
                for (int ns = 0; ns < 4; ++ns) {
                    unsigned short hv = f2bf(v4[ns]);
                    hi_p[base + ns * 16 + lr] = hv;
                    if (path == 0)
                        qlo[base + ns * 16 + lr] = f2bf(v4[ns] - bf2f(hv));
                }
            }
    } else {
        // V path: in-LDS transpose, write vt[bh][d][s] directly.
        __syncthreads();                          // staging reads all retired
        float bias_v[4];
        #pragma unroll
        for (int ns = 0; ns < 4; ++ns) bias_v[ns] = bv[c0 + wx * 64 + ns * 16 + lr];
        #pragma unroll
        for (int mg = 0; mg < 4; ++mg)
            #pragma unroll
            for (int r = 0; r < 4; ++r) {
                int mloc = wy * 64 + mg * 16 + quad * 4 + r;
                #pragma unroll
                for (int ns = 0; ns < 4; ++ns) {
                    int cloc = wx * 64 + ns * 16 + lr;
                    SH[cloc * 136 + mloc] = f2bf(acc[mg][ns][r] + bias_v[ns]);
                }
            }
        __syncthreads();
        const int b = m0 >> 11, s0 = m0 & (SS - 1);
        #pragma unroll
        for (int jc = 0; jc < 8; ++jc) {
            int cl = (t >> 4) + jc * 16;          // transposed line 0..127
            int sl = (t & 15) * 8;                // 16 lanes cover 128 s
            bf16x8 vv = *(const bf16x8*)&SH[cl * 136 + sl];
            int c = c0 + cl, h = c >> 6, d = c & 63;
            *(bf16x8*)&vt[((size_t)(b * HH + h) * DD + d) * SS + s0 + sl] = vv;
        }
    }
}

// bf16 MFMA GEMM (O-projection, 1-pass, BK=32 — round-8 form).
__global__ __launch_bounds__(256, 2) void gemm_o(
        const unsigned short* __restrict__ Ahi,
        const unsigned short* __restrict__ Bhi,
        const float* __restrict__ bq,
        float* __restrict__ Cf,
        int M, int N, int K) {
    __shared__ __align__(16) unsigned short LA_hi[128 * 32];
    __shared__ __align__(16) unsigned short LB_hi[128 * 32];

    const int t = threadIdx.x;
    const int w = t >> 6, lane = t & 63;
    const int quad = lane >> 4, lr = lane & 15;
    const int wy = w & 1, wx = w >> 1;
    const int m0 = blockIdx.y * 128, n0 = blockIdx.x * 128;

    const unsigned short* gsrc = nullptr;
    unsigned short* ldst = nullptr;
    if (w == 0)      { gsrc = Ahi + (size_t)m0 * K; ldst = LA_hi; }
    else if (w == 2) { gsrc = Bhi + (size_t)n0 * K; ldst = LB_hi; }
    const unsigned short* gl = gsrc ? gsrc + (size_t)(lane >> 2) * K + (lane & 3) * 8
                                    : nullptr;

    f32x4 acc[4][4];
    #pragma unroll
    for (int i = 0; i < 4; ++i)
        #pragma unroll
        for (int j = 0; j < 4; ++j)
            acc[i][j] = (f32x4){0.f, 0.f, 0.f, 0.f};

    for (int k0 = 0; k0 < K; k0 += 32) {
        __syncthreads();
        if (gl) {
            #pragma unroll
            for (int i = 0; i < 8; ++i)
                async_ld16(ldst + i * 512, gl + (size_t)i * 16 * K + k0);
        }
        __syncthreads();
        bf16x8 ah[4], bh_[4];
        #pragma unroll
        for (int i = 0; i < 4; ++i) {
            ah[i]  = *(const bf16x8*)&LA_hi[(wy * 64 + i * 16 + lr) * 32 + quad * 8];
            bh_[i] = *(const bf16x8*)&LB_hi[(wx * 64 + i * 16 + lr) * 32 + quad * 8];
        }
        #pragma unroll
        for (int mg = 0; mg < 4; ++mg)
            #pragma unroll
            for (int ns = 0; ns < 4; ++ns)
                acc[mg][ns] = MFMA16(ah[mg], bh_[ns], acc[mg][ns]);
    }

    const int ng = n0 + wx * 64;
    float bias_v[4];
    #pragma unroll
    for (int ns = 0; ns < 4; ++ns) bias_v[ns] = bq[ng + ns * 16 + lr];
    #pragma unroll
    for (int mg = 0; mg < 4; ++mg)
        #pragma unroll
        for (int r = 0; r < 4; ++r) {
            int m = m0 + wy * 64 + mg * 16 + quad * 4 + r;
            #pragma unroll
            for (int ns = 0; ns < 4; ++ns)
                Cf[(size_t)m * N + ng + ns * 16 + lr] = acc[mg][ns][r] + bias_v[ns];
        }
}

// MFMA flash attention v15 (round-8 measured best: 159.2us, VGPR 64,
// LDS 25088, WRITE 8.2MB, zero conflicts) — restored VERBATIM.
// z=1 (32 tiles/block, 1024 blocks), fused normalize + bf16 ctx epilogue.
// K staged via global_load_lds, XOR-swizzled, double-buffered, 64-key tile
// per buffer, full-tile prefetch distance. Ps single-buffered. defer-max.
// Session conclusion: this kernel is latency-bound at a structural plateau
// (~159us): 7 variants falsified — no-staging (v10 +100us), +occupancy
// (v12/v17 +-0), reg-dbuf (v13 spill), barrier-free (v14 +30us + outlier),
// z-splits, wave-geometry. Occupancy pinned at 4 waves/SIMD by unified
// VGPR+AGPR step function; below-natural launch_bounds caps spill (3x).
__global__ __launch_bounds__(256, 4) void yat_attn_mfma(
        const unsigned short* __restrict__ qhi, const unsigned short* __restrict__ qlo,
        const unsigned short* __restrict__ khi,
        const unsigned short* __restrict__ vt,
        const float* __restrict__ sqn, const float* __restrict__ skn,
        const float* __restrict__ alphap,
        unsigned short* __restrict__ ctxhi) {
    __shared__ __align__(16) unsigned short Ks[2][4096];     // [dbuf][64k x 64d] 16KB
    __shared__ __align__(16) unsigned short Ps[4][16 * 68];  // [wave] 8.7KB

    const int t = threadIdx.x;
    const int w = t >> 6, lane = t & 63;
    const int quad = lane >> 4, lr = lane & 15;
    const int qt = blockIdx.x, bh = blockIdx.y;
    const int row0 = qt * 64 + w * 16;
    const float cscale = powf(sqrtf((float)DD) / log1pf((float)DD), alphap[0])
                         * 1.4426950408889634f;

    bf16x8 qh[2], ql[2];
    #pragma unroll
    for (int kd = 0; kd < 2; ++kd) {
        size_t o = ((size_t)bh * SS + row0 + lr) * DD + kd * 32 + quad * 8;
        qh[kd] = *(const bf16x8*)&qhi[o];
        ql[kd] = *(const bf16x8*)&qlo[o];
    }
    const float sqe = sqn[(size_t)bh * SS + row0 + lr] + YAT_EPS;

    const int lrow = lane >> 3;
    const int lofs = lrow * 64 + (((lane & 7) ^ (lrow & 7)) << 3);
    const int sw = lr & 7;

    float m_r = -INFINITY, l_r = 0.f;   // m_r in u-domain
    f32x4 O[4];
    #pragma unroll
    for (int nd = 0; nd < 4; ++nd) O[nd] = (f32x4){0.f, 0.f, 0.f, 0.f};

    const size_t khi_base = (size_t)bh * SS * 64 + (size_t)w * 16 * 64 + lofs;
    const size_t skn_base = (size_t)bh * SS + quad * 4;
    unsigned short* myP = Ps[w];

    // prologue: stage tile 0 into buffer 0 (wave w stages rows w*16..+15)
    #pragma unroll
    for (int i2 = 0; i2 < 2; ++i2)
        async_ld16(&Ks[0][w * 1024 + i2 * 512], khi + khi_base + i2 * 512);

    for (int it = 0; it < 32; ++it) {
        const int p = it & 1;
        __syncthreads();           // drains vmcnt: buffer p is ready
        if (it + 1 < 32) {
            #pragma unroll
            for (int i2 = 0; i2 < 2; ++i2)
                async_ld16(&Ks[p ^ 1][w * 1024 + i2 * 512],
                           khi + khi_base + (size_t)(it + 1) * 4096 + i2 * 512);
        }
        const int kbase = it * 64;
        const unsigned short* kb = Ks[p];
        f32x4 acc[4];
        f32x4 sk4[4];
        #pragma unroll
        for (int st = 0; st < 4; ++st) {
            const int rbase = (st * 16 + lr) * 64;
            bf16x8 kh0 = *(const bf16x8*)&kb[rbase + ((quad    ) ^ sw) * 8];
            bf16x8 kh1 = *(const bf16x8*)&kb[rbase + ((quad + 4) ^ sw) * 8];
            sk4[st] = *(const f32x4*)&skn[skn_base + kbase + st * 16];
            f32x4 a = (f32x4){0.f, 0.f, 0.f, 0.f};
            a = MFMA16(kh0, qh[0], a);
            a = MFMA16(kh1, qh[1], a);
            a = MFMA16(kh0, ql[0], a);
            a = MFMA16(kh1, ql[1], a);
            acc[st] = a;
        }
        bf16x8 vf[4][2];
        #pragma unroll
        for (int nd = 0; nd < 4; ++nd)
            #pragma unroll
            for (int kk = 0; kk < 2; ++kk)
                vf[nd][kk] = *(const bf16x8*)&vt[((size_t)bh * DD + nd * 16 + lr) * SS
                                                 + kbase + kk * 32 + quad * 8];
        float mx = -INFINITY;
        #pragma unroll
        for (int st = 0; st < 4; ++st)
            #pragma unroll
            for (int r = 0; r < 4; ++r) {
                float qk = acc[st][r];
                float d = sqe + sk4[st][r] - 2.f * qk;
                float u = qk * qk * RCPF(d);
                acc[st][r] = u;
                mx = fmaxf(mx, u);
            }
        mx = fmaxf(mx, __shfl_xor(mx, 16));
        mx = fmaxf(mx, __shfl_xor(mx, 32));
        float mnew = fmaxf(m_r, mx);
        // defer-max: only rescale when some row's max grew by >8 (exp2 domain)
        bool resc = !__all(cscale * (mnew - m_r) <= 8.f);
        float aa = 1.f;
        if (resc) {
            aa = EXP2(__builtin_fmaf(cscale, m_r, -cscale * mnew));
            m_r = mnew;
        }
        const float cm = cscale * m_r;
        float rs = 0.f;
        #pragma unroll
        for (int st = 0; st < 4; ++st) {
            float e0 = EXP2(__builtin_fmaf(cscale, acc[st][0], -cm));
            float e1 = EXP2(__builtin_fmaf(cscale, acc[st][1], -cm));
            float e2 = EXP2(__builtin_fmaf(cscale, acc[st][2], -cm));
            float e3 = EXP2(__builtin_fmaf(cscale, acc[st][3], -cm));
            rs += (e0 + e1) + (e2 + e3);
            short4v pv;
            pv[0] = f2bf_t(e0); pv[1] = f2bf_t(e1);
            pv[2] = f2bf_t(e2); pv[3] = f2bf_t(e3);
            *(short4v*)&myP[lr * 68 + st * 16 + quad * 4] = pv;
        }
        rs += __shfl_xor(rs, 16);
        rs += __shfl_xor(rs, 32);
        l_r = l_r * aa + rs;
        if (resc) {
            float al_[4];
            #pragma unroll
            for (int r = 0; r < 4; ++r) al_[r] = __shfl(aa, quad * 4 + r);
            #pragma unroll
            for (int nd = 0; nd < 4; ++nd)
                #pragma unroll
                for (int r = 0; r < 4; ++r)
                    O[nd][r] *= al_[r];
        }
        bf16x8 pf[2];
        #pragma unroll
        for (int kk = 0; kk < 2; ++kk)
            pf[kk] = *(const bf16x8*)&myP[lr * 68 + kk * 32 + quad * 8];
        #pragma unroll
        for (int nd = 0; nd < 4; ++nd)
            #pragma unroll
            for (int kk = 0; kk < 2; ++kk)
                O[nd] = MFMA16(pf[kk], vf[nd][kk], O[nd]);
    }
    // fused epilogue: normalize by 1/l and write ctx bf16 directly.
    const int b = bh >> 4, h = bh & 15;
    #pragma unroll
    for (int r = 0; r < 4; ++r) {
        float li = __shfl(l_r, quad * 4 + r);
        float inv = RCPF(li);
        int s = row0 + quad * 4 + r;
        size_t base = ((size_t)b * SS + s) * EE + h * DD;
        #pragma unroll
        for (int nd = 0; nd < 4; ++nd)
            ctxhi[base + nd * 16 + lr] = f2bf(O[nd][r] * inv);
    }
}

extern "C" void kernel_launch(void* const* d_in, const int* in_sizes, int n_in,
                              void* d_out, int out_size, void* d_ws, size_t ws_size,
                              hipStream_t stream) {
    const float* x     = (const float*)d_in[0];
    const float* Wq    = (const float*)d_in[1];
    const float* bq    = (const float*)d_in[2];
    const float* Wk    = (const float*)d_in[3];
    const float* bk    = (const float*)d_in[4];
    const float* Wv    = (const float*)d_in[5];
    const float* bv    = (const float*)d_in[6];
    const float* Wo    = (const float*)d_in[7];
    const float* bo    = (const float*)d_in[8];
    const float* alpha = (const float*)d_in[9];
    float* out = (float*)d_out;
    char* ws = (char*)d_ws;

    const int M = BB * SS;                 // 4096
    const size_t MB = 1u << 20;
    unsigned short* xhi  = (unsigned short*)(ws + 0 * MB);   // later: ctxhi
    unsigned short* xlo  = (unsigned short*)(ws + 8 * MB);
    unsigned short* Whi  = (unsigned short*)(ws + 16 * MB);  // 6 MB (qkv concat)
    unsigned short* Wlo  = (unsigned short*)(ws + 22 * MB);  // 4 MB used (q,k)
    unsigned short* Wohi = (unsigned short*)(ws + 28 * MB);
    unsigned short* qhi  = (unsigned short*)(ws + 32 * MB);
    unsigned short* qlo  = (unsigned short*)(ws + 40 * MB);
    unsigned short* khi  = (unsigned short*)(ws + 48 * MB);  // 8 MB
    unsigned short* vt   = (unsigned short*)(ws + 56 * MB);  // 8 MB
    float* sqn = (float*)(ws + 80 * MB);
    float* skn = (float*)(ws + 80 * MB + 256 * 1024);
    unsigned short* ctxhi = xhi;           // xhi dead after proj_qkv

    split_all<<<8192, 256, 0, stream>>>(x, Wq, Wk, Wv, Wo,
                                        xhi, xlo, Whi, Wlo, Wohi);

    // Fused Q/K (3-pass Markidis) + V (1-pass, transposed-write) projection
    proj_qkv<<<dim3(24, M / 128), 256, 0, stream>>>(
        xhi, xlo, Whi, Wlo, bq, bk, bv,
        qhi, qlo, khi, vt, sqn, skn);

    // attention (single K-range pass, fused normalize + ctx write)
    yat_attn_mfma<<<dim3(SS / 64, BB * HH), 256, 0, stream>>>(
        qhi, qlo, khi, vt, sqn, skn, alpha, ctxhi);

    // O projection: plain bf16 (error ~6e-4 ≪ threshold)
    gemm_o<<<dim3(EE / 128, M / 128), 256, 0, stream>>>(
        ctxhi, Wohi, bo, out, M, EE, EE);
}